// Round 3
// baseline (847.157 us; speedup 1.0000x reference)
//
#include <hip/hip_runtime.h>
#include <hip/hip_fp16.h>
#include <hip/hip_cooperative_groups.h>

namespace cg = cooperative_groups;

#define N_NODES 10000
#define N_EDGES 640000
#define N_GRAPHS 64
#define FEATS 128

#define NSLICE 64
#define EPS (N_EDGES / NSLICE)   // 10000 edges per slice
#define CAP 128                  // padded per-node edge capacity (mean deg 64; 128 = +8sigma)
#define NBLK 512                 // 2 blocks/CU x 256 CUs; 80KB LDS of 160 -> safe co-residency
#define NTILE (N_NODES / 16)     // 625 GEMM tiles of 16 nodes
#define PRE_BLOCKS 1250          // fallback path: 320000 float4 / 256

static inline size_t align_up(size_t x, size_t a) { return (x + a - 1) & ~(a - 1); }

// ---------------------------------------------------------------------------
// accumulate one 256B fp16 row (held as uint4 per 16-lane group) into fp32 acc
static __device__ __forceinline__ void acc_row(uint4 v, float* a) {
    const __half2* hp = (const __half2*)&v;
#pragma unroll
    for (int j = 0; j < 4; j++) {
        float2 f = __half22float2(hp[j]);
        a[2 * j]     += f.x;
        a[2 * j + 1] += f.y;
    }
}

// one batch: 4 edges for this quarter-group (16 rows in flight across the wave)
static __device__ __forceinline__ void agg_batch(const int* __restrict__ ss,
                                                 const uint4* __restrict__ x4,
                                                 int base, int c, int l16, float* a) {
    int idx[4];
#pragma unroll
    for (int k = 0; k < 4; k++) idx[k] = ss[base + c + 4 * k];
    uint4 v[4];
#pragma unroll
    for (int k = 0; k < 4; k++) v[k] = x4[idx[k] * 16 + l16];
#pragma unroll
    for (int k = 0; k < 4; k++) acc_row(v[k], a);
}

// Aggregate TWO dst nodes per wave concurrently. Quarter-wave (16 lanes x 16B)
// fetches one 256B fp16 row; group grp handles edges == grp (mod 4).
// Results (x norm) land in LDS fp32 rows r0/r1. Numerically identical to the
// single-node R0/R1 version (same per-node edge order + shuffle combine).
static __device__ __forceinline__ void wave_aggregate2(const __half* __restrict__ X,
                                                       const int* __restrict__ ss,
                                                       const int* __restrict__ deg_in,
                                                       const float* __restrict__ nrm,
                                                       int n0, int n1, int lane,
                                                       float* __restrict__ r0,
                                                       float* __restrict__ r1) {
    const int grp = lane >> 4, l16 = lane & 15;
    const int s0 = n0 * CAP, s1 = n1 * CAP;
    const int c0n = deg_in[n0], c1n = deg_in[n1];
    const uint4* __restrict__ x4 = (const uint4*)X;  // row = 16 uint4 (256 B)
    float a0[8] = {0.f, 0.f, 0.f, 0.f, 0.f, 0.f, 0.f, 0.f};
    float a1[8] = {0.f, 0.f, 0.f, 0.f, 0.f, 0.f, 0.f, 0.f};
    int c0 = grp, c1 = grp;
    while (c0 + 12 < c0n && c1 + 12 < c1n) {
        agg_batch(ss, x4, s0, c0, l16, a0);
        agg_batch(ss, x4, s1, c1, l16, a1);
        c0 += 16; c1 += 16;
    }
    for (; c0 + 12 < c0n; c0 += 16) agg_batch(ss, x4, s0, c0, l16, a0);
    for (; c1 + 12 < c1n; c1 += 16) agg_batch(ss, x4, s1, c1, l16, a1);
    for (; c0 < c0n; c0 += 4) acc_row(x4[ss[s0 + c0] * 16 + l16], a0);
    for (; c1 < c1n; c1 += 4) acc_row(x4[ss[s1 + c1] * 16 + l16], a1);
#pragma unroll
    for (int j = 0; j < 8; j++) {
        a0[j] += __shfl_xor(a0[j], 16);
        a0[j] += __shfl_xor(a0[j], 32);
        a1[j] += __shfl_xor(a1[j], 16);
        a1[j] += __shfl_xor(a1[j], 32);
    }
    if (grp == 0) {
        const float nd0 = nrm[n0], nd1 = nrm[n1];
        *(float4*)(r0 + l16 * 8)     = make_float4(a0[0] * nd0, a0[1] * nd0, a0[2] * nd0, a0[3] * nd0);
        *(float4*)(r0 + l16 * 8 + 4) = make_float4(a0[4] * nd0, a0[5] * nd0, a0[6] * nd0, a0[7] * nd0);
        *(float4*)(r1 + l16 * 8)     = make_float4(a1[0] * nd1, a1[1] * nd1, a1[2] * nd1, a1[3] * nd1);
        *(float4*)(r1 + l16 * 8 + 4) = make_float4(a1[4] * nd1, a1[5] * nd1, a1[6] * nd1, a1[7] * nd1);
    }
}

// GEMM inner: 2 rows (r, r+8) x 4 cols from LDS As against W, fp32 acc
static __device__ __forceinline__ void gemm_2x4(const float* __restrict__ a0p,
                                                const float* __restrict__ a1p,
                                                const float* __restrict__ W, int fg,
                                                float4& acc0, float4& acc1) {
#pragma unroll 4
    for (int k = 0; k < FEATS; k++) {
        float a0 = a0p[k];
        float a1 = a1p[k];
        float4 w = *(const float4*)(W + k * FEATS + fg);
        acc0.x = fmaf(a0, w.x, acc0.x); acc0.y = fmaf(a0, w.y, acc0.y);
        acc0.z = fmaf(a0, w.z, acc0.z); acc0.w = fmaf(a0, w.w, acc0.w);
        acc1.x = fmaf(a1, w.x, acc1.x); acc1.y = fmaf(a1, w.y, acc1.y);
        acc1.z = fmaf(a1, w.z, acc1.z); acc1.w = fmaf(a1, w.w, acc1.w);
    }
}

// ===========================================================================
// COOPERATIVE MONO-KERNEL
// Phases: P0 hist | P1 degnorm+bases | P2 scatter+prescale | P3 layer1 |
//         P4 layer2+pool | P5 final.  Explicit agent-scope fences around every
//         grid.sync (per-XCD L2 non-coherence: Guideline 16 — R2's failure).
__global__ __launch_bounds__(256, 2) void gcn_mono(
    const float* __restrict__ in_feat, const int* __restrict__ src,
    const int* __restrict__ dst, const int* __restrict__ gids,
    const float* __restrict__ W1, const float* __restrict__ b1,
    const float* __restrict__ W2, const float* __restrict__ b2,
    const float* __restrict__ Wd, const float* __restrict__ bd,
    float* __restrict__ out,
    unsigned short* __restrict__ counts, unsigned short* __restrict__ scounts,
    int* __restrict__ bases, int* __restrict__ deg_in,
    float* __restrict__ norm_src, float* __restrict__ norm_dst,
    int* __restrict__ sorted_src, __half* __restrict__ xs, __half* __restrict__ h,
    int* __restrict__ graph_cnt, float* __restrict__ graph_sum) {
    cg::grid_group grid = cg::this_grid();
    __shared__ int S[10240];  // 40 KB union: hist / cursors / GEMM As + bins
    const int tid = threadIdx.x;
    const int b = blockIdx.x;
    const int wave = tid >> 6, lane = tid & 63;
    float* const As = (float*)S;

    // ---- P0: per-slice LDS histograms: dst (blocks 0..63), src (64..127) ----
    if (b < 2 * NSLICE) {
        const bool is_dst = (b < NSLICE);
        const int slice = is_dst ? b : b - NSLICE;
        const int* col = is_dst ? dst : src;
        unsigned short* outp = (is_dst ? counts : scounts) + slice * N_NODES;
        for (int i = tid; i < N_NODES; i += 256) S[i] = 0;
        __syncthreads();
        const int4* c4 = (const int4*)(col + slice * EPS);
        for (int i = tid; i < EPS / 4; i += 256) {
            int4 v = c4[i];
            atomicAdd(&S[v.x], 1);
            atomicAdd(&S[v.y], 1);
            atomicAdd(&S[v.z], 1);
            atomicAdd(&S[v.w], 1);
        }
        __syncthreads();
        for (int i = tid; i < N_NODES; i += 256) outp[i] = (unsigned short)S[i];
    } else if (b == 2 * NSLICE) {
        if (tid < N_GRAPHS) graph_cnt[tid] = 0;
        else if (tid < 2 * N_GRAPHS) graph_sum[tid - N_GRAPHS] = 0.f;
    }
    __threadfence(); grid.sync(); __threadfence();

    // ---- P1: scan counts -> bases; degrees, norms, graph counts ----
    {
        if (tid < N_GRAPHS) S[tid] = 0;
        __syncthreads();
        const int n = b * 256 + tid;  // blocks 0..39 carry nodes
        if (n < N_NODES) {
            int run = n * CAP;
            for (int s = 0; s < NSLICE; s++) {
                int c = counts[s * N_NODES + n];
                bases[s * N_NODES + n] = run;
                run += c;
            }
            const int di = run - n * CAP;
            int dou = 0;
            for (int s = 0; s < NSLICE; s++) dou += scounts[s * N_NODES + n];
            deg_in[n] = di;
            norm_dst[n] = rsqrtf((float)(di < 1 ? 1 : di));
            norm_src[n] = rsqrtf((float)(dou < 1 ? 1 : dou));
            atomicAdd(&S[gids[n]], 1);
        }
        __syncthreads();
        if (tid < N_GRAPHS && S[tid]) atomicAdd(&graph_cnt[tid], S[tid]);
    }
    __threadfence(); grid.sync(); __threadfence();

    // ---- P2: scatter edges into padded CSR (0..63) + prescale xs (64..511) ----
    if (b < NSLICE) {
        for (int i = tid; i < N_NODES; i += 256) S[i] = bases[b * N_NODES + i];
        __syncthreads();
        const int4* s4 = (const int4*)(src + b * EPS);
        const int4* d4 = (const int4*)(dst + b * EPS);
        for (int i = tid; i < EPS / 4; i += 256) {
            int4 sv = s4[i];
            int4 dv = d4[i];
            int p;
            p = atomicAdd(&S[dv.x], 1); sorted_src[p] = sv.x;
            p = atomicAdd(&S[dv.y], 1); sorted_src[p] = sv.y;
            p = atomicAdd(&S[dv.z], 1); sorted_src[p] = sv.z;
            p = atomicAdd(&S[dv.w], 1); sorted_src[p] = sv.w;
        }
    } else {
        for (int i = (b - NSLICE) * 256 + tid; i < N_NODES * (FEATS / 4);
             i += (NBLK - NSLICE) * 256) {
            int n = i >> 5;
            float4 v = ((const float4*)in_feat)[i];
            float s = norm_src[n];
            __half2* o = (__half2*)(xs + (size_t)i * 4);
            o[0] = __floats2half2_rn(v.x * s, v.y * s);
            o[1] = __floats2half2_rn(v.z * s, v.w * s);
        }
    }
    __threadfence(); grid.sync(); __threadfence();

    // ---- P3: layer1 — aggregate 16 nodes to LDS fp32, GEMM W1, relu, x norm_src ----
    for (int t = b; t < NTILE; t += NBLK) {
        const int nb = t * 16;
#pragma unroll
        for (int p = 0; p < 2; p++) {
            int ln0 = wave * 4 + 2 * p;
            wave_aggregate2(xs, sorted_src, deg_in, norm_dst, nb + ln0, nb + ln0 + 1,
                            lane, As + ln0 * FEATS, As + (ln0 + 1) * FEATS);
        }
        __syncthreads();
        const int fg = (tid & 31) << 2;
        const int r = tid >> 5;
        float4 acc0 = make_float4(0.f, 0.f, 0.f, 0.f);
        float4 acc1 = make_float4(0.f, 0.f, 0.f, 0.f);
        gemm_2x4(As + r * FEATS, As + (r + 8) * FEATS, W1, fg, acc0, acc1);
        float4 bb = *(const float4*)(b1 + fg);
        const int gn0 = nb + r, gn1 = nb + r + 8;
        const float s0 = norm_src[gn0], s1 = norm_src[gn1];
        __half2 h00 = __floats2half2_rn(fmaxf(acc0.x + bb.x, 0.f) * s0,
                                        fmaxf(acc0.y + bb.y, 0.f) * s0);
        __half2 h01 = __floats2half2_rn(fmaxf(acc0.z + bb.z, 0.f) * s0,
                                        fmaxf(acc0.w + bb.w, 0.f) * s0);
        __half2 h10 = __floats2half2_rn(fmaxf(acc1.x + bb.x, 0.f) * s1,
                                        fmaxf(acc1.y + bb.y, 0.f) * s1);
        __half2 h11 = __floats2half2_rn(fmaxf(acc1.z + bb.z, 0.f) * s1,
                                        fmaxf(acc1.w + bb.w, 0.f) * s1);
        __half2* o0 = (__half2*)(h + (size_t)gn0 * FEATS + fg);
        __half2* o1 = (__half2*)(h + (size_t)gn1 * FEATS + fg);
        o0[0] = h00; o0[1] = h01;
        o1[0] = h10; o1[1] = h11;
        __syncthreads();  // As reused next tile iteration
    }
    __threadfence(); grid.sync(); __threadfence();

    // ---- P4: layer2 — aggregate h, GEMM W2, relu, dot Wd, pool ----
    for (int t = b; t < NTILE; t += NBLK) {
        float* bins = As + 2048;  // disjoint from the 16x128 As rows
        if (tid < N_GRAPHS) bins[tid] = 0.f;
        const int nb = t * 16;
#pragma unroll
        for (int p = 0; p < 2; p++) {
            int ln0 = wave * 4 + 2 * p;
            wave_aggregate2(h, sorted_src, deg_in, norm_dst, nb + ln0, nb + ln0 + 1,
                            lane, As + ln0 * FEATS, As + (ln0 + 1) * FEATS);
        }
        __syncthreads();
        const int fg = (tid & 31) << 2;
        const int r = tid >> 5;
        float4 acc0 = make_float4(0.f, 0.f, 0.f, 0.f);
        float4 acc1 = make_float4(0.f, 0.f, 0.f, 0.f);
        gemm_2x4(As + r * FEATS, As + (r + 8) * FEATS, W2, fg, acc0, acc1);
        float4 bb = *(const float4*)(b2 + fg);
        float4 wd = *(const float4*)(Wd + fg);
        float p0 = fmaxf(acc0.x + bb.x, 0.f) * wd.x + fmaxf(acc0.y + bb.y, 0.f) * wd.y +
                   fmaxf(acc0.z + bb.z, 0.f) * wd.z + fmaxf(acc0.w + bb.w, 0.f) * wd.w;
        float p1 = fmaxf(acc1.x + bb.x, 0.f) * wd.x + fmaxf(acc1.y + bb.y, 0.f) * wd.y +
                   fmaxf(acc1.z + bb.z, 0.f) * wd.z + fmaxf(acc1.w + bb.w, 0.f) * wd.w;
#pragma unroll
        for (int d = 16; d >= 1; d >>= 1) {
            p0 += __shfl_down(p0, d);
            p1 += __shfl_down(p1, d);
        }
        if ((tid & 31) == 0) {
            atomicAdd(&bins[gids[nb + r]], p0);
            atomicAdd(&bins[gids[nb + r + 8]], p1);
        }
        __syncthreads();
        if (tid < N_GRAPHS) {
            float v = bins[tid];
            if (v != 0.f) atomicAdd(&graph_sum[tid], v);
        }
        __syncthreads();  // bins re-zeroed next tile iteration
    }
    __threadfence(); grid.sync(); __threadfence();

    // ---- P5: final ----
    if (b == 0 && tid < N_GRAPHS) {
        out[tid] = graph_sum[tid] / fmaxf((float)graph_cnt[tid], 1.f) + bd[0];
    }
}

// ===========================================================================
// FALLBACK multi-dispatch path (known-passing R0/R1 structure), used only if
// the cooperative launch is rejected.
__global__ __launch_bounds__(256) void hist_kernel(const int* __restrict__ src,
                                                   const int* __restrict__ dst,
                                                   unsigned short* __restrict__ counts,
                                                   unsigned short* __restrict__ scounts,
                                                   int* __restrict__ graph_cnt,
                                                   float* __restrict__ graph_sum) {
    __shared__ int hs[N_NODES];
    const int tid = threadIdx.x;
    const int b = blockIdx.x;
    if (b == 0 && tid < 2 * N_GRAPHS) {
        if (tid < N_GRAPHS) graph_cnt[tid] = 0;
        else                graph_sum[tid - N_GRAPHS] = 0.f;
    }
    const bool is_dst = (b < NSLICE);
    const int slice = is_dst ? b : b - NSLICE;
    const int* col = is_dst ? dst : src;
    unsigned short* outp = (is_dst ? counts : scounts) + slice * N_NODES;
    for (int i = tid; i < N_NODES; i += 256) hs[i] = 0;
    __syncthreads();
    const int4* c4 = (const int4*)(col + slice * EPS);
    for (int i = tid; i < EPS / 4; i += 256) {
        int4 v = c4[i];
        atomicAdd(&hs[v.x], 1);
        atomicAdd(&hs[v.y], 1);
        atomicAdd(&hs[v.z], 1);
        atomicAdd(&hs[v.w], 1);
    }
    __syncthreads();
    for (int i = tid; i < N_NODES; i += 256) outp[i] = (unsigned short)hs[i];
}

__global__ __launch_bounds__(256) void degnorm_base_kernel(const unsigned short* __restrict__ counts,
                                                           const unsigned short* __restrict__ scounts,
                                                           const int* __restrict__ gids,
                                                           int* __restrict__ bases,
                                                           int* __restrict__ deg_in,
                                                           float* __restrict__ norm_src,
                                                           float* __restrict__ norm_dst,
                                                           int* __restrict__ graph_cnt) {
    __shared__ int gcnt[N_GRAPHS];
    const int tid = threadIdx.x;
    if (tid < N_GRAPHS) gcnt[tid] = 0;
    __syncthreads();
    int n = blockIdx.x * 256 + tid;
    if (n < N_NODES) {
        int run = n * CAP;
        for (int s = 0; s < NSLICE; s++) {
            int c = counts[s * N_NODES + n];
            bases[s * N_NODES + n] = run;
            run += c;
        }
        int di = run - n * CAP;
        int dou = 0;
        for (int s = 0; s < NSLICE; s++) dou += scounts[s * N_NODES + n];
        deg_in[n] = di;
        norm_dst[n] = rsqrtf((float)(di < 1 ? 1 : di));
        norm_src[n] = rsqrtf((float)(dou < 1 ? 1 : dou));
        atomicAdd(&gcnt[gids[n]], 1);
    }
    __syncthreads();
    if (tid < N_GRAPHS && gcnt[tid]) atomicAdd(&graph_cnt[tid], gcnt[tid]);
}

__global__ __launch_bounds__(256) void scatter_prescale_kernel(const int* __restrict__ src,
                                                               const int* __restrict__ dst,
                                                               const int* __restrict__ bases,
                                                               int* __restrict__ sorted_src,
                                                               const float* __restrict__ in_feat,
                                                               const float* __restrict__ norm_src,
                                                               __half* __restrict__ xs) {
    const int tid = threadIdx.x;
    if (blockIdx.x < NSLICE) {
        __shared__ int cur[N_NODES];
        const int s = blockIdx.x;
        for (int i = tid; i < N_NODES; i += 256) cur[i] = bases[s * N_NODES + i];
        __syncthreads();
        const int4* s4 = (const int4*)(src + s * EPS);
        const int4* d4 = (const int4*)(dst + s * EPS);
        for (int i = tid; i < EPS / 4; i += 256) {
            int4 sv = s4[i];
            int4 dv = d4[i];
            int p;
            p = atomicAdd(&cur[dv.x], 1); sorted_src[p] = sv.x;
            p = atomicAdd(&cur[dv.y], 1); sorted_src[p] = sv.y;
            p = atomicAdd(&cur[dv.z], 1); sorted_src[p] = sv.z;
            p = atomicAdd(&cur[dv.w], 1); sorted_src[p] = sv.w;
        }
    } else {
        int i = (blockIdx.x - NSLICE) * 256 + tid;
        if (i < N_NODES * (FEATS / 4)) {
            int n = i >> 5;
            float4 v = ((const float4*)in_feat)[i];
            float s = norm_src[n];
            __half2* o = (__half2*)(xs + (size_t)i * 4);
            o[0] = __floats2half2_rn(v.x * s, v.y * s);
            o[1] = __floats2half2_rn(v.z * s, v.w * s);
        }
    }
}

__global__ __launch_bounds__(256) void fused_layer1_kernel(const __half* __restrict__ xs,
                                                           const int* __restrict__ sorted_src,
                                                           const int* __restrict__ deg_in,
                                                           const float* __restrict__ norm_dst,
                                                           const float* __restrict__ W,
                                                           const float* __restrict__ bias,
                                                           const float* __restrict__ scale,
                                                           __half* __restrict__ out) {
    __shared__ float As[16 * FEATS];
    const int tid = threadIdx.x;
    const int nb = blockIdx.x * 16;
    const int wave = tid >> 6, lane = tid & 63;
#pragma unroll
    for (int p = 0; p < 2; p++) {
        int ln0 = wave * 4 + 2 * p;
        wave_aggregate2(xs, sorted_src, deg_in, norm_dst, nb + ln0, nb + ln0 + 1,
                        lane, As + ln0 * FEATS, As + (ln0 + 1) * FEATS);
    }
    __syncthreads();
    const int fg = (tid & 31) << 2;
    const int r = tid >> 5;
    float4 acc0 = make_float4(0.f, 0.f, 0.f, 0.f);
    float4 acc1 = make_float4(0.f, 0.f, 0.f, 0.f);
    gemm_2x4(As + r * FEATS, As + (r + 8) * FEATS, W, fg, acc0, acc1);
    float4 bb = *(const float4*)(bias + fg);
    const int gn0 = nb + r, gn1 = nb + r + 8;
    const float s0 = scale[gn0], s1 = scale[gn1];
    __half2 h00 = __floats2half2_rn(fmaxf(acc0.x + bb.x, 0.f) * s0,
                                    fmaxf(acc0.y + bb.y, 0.f) * s0);
    __half2 h01 = __floats2half2_rn(fmaxf(acc0.z + bb.z, 0.f) * s0,
                                    fmaxf(acc0.w + bb.w, 0.f) * s0);
    __half2 h10 = __floats2half2_rn(fmaxf(acc1.x + bb.x, 0.f) * s1,
                                    fmaxf(acc1.y + bb.y, 0.f) * s1);
    __half2 h11 = __floats2half2_rn(fmaxf(acc1.z + bb.z, 0.f) * s1,
                                    fmaxf(acc1.w + bb.w, 0.f) * s1);
    __half2* o0 = (__half2*)(out + (size_t)gn0 * FEATS + fg);
    __half2* o1 = (__half2*)(out + (size_t)gn1 * FEATS + fg);
    o0[0] = h00; o0[1] = h01;
    o1[0] = h10; o1[1] = h11;
}

__global__ __launch_bounds__(256) void fused_layer2_kernel(const __half* __restrict__ hbuf,
                                                           const int* __restrict__ sorted_src,
                                                           const int* __restrict__ deg_in,
                                                           const float* __restrict__ norm_dst,
                                                           const float* __restrict__ W,
                                                           const float* __restrict__ bias,
                                                           const float* __restrict__ Wd,
                                                           const int* __restrict__ gids,
                                                           float* __restrict__ graph_sum) {
    __shared__ float As[16 * FEATS];
    __shared__ float bins[N_GRAPHS];
    const int tid = threadIdx.x;
    const int nb = blockIdx.x * 16;
    const int wave = tid >> 6, lane = tid & 63;
    if (tid < N_GRAPHS) bins[tid] = 0.f;
#pragma unroll
    for (int p = 0; p < 2; p++) {
        int ln0 = wave * 4 + 2 * p;
        wave_aggregate2(hbuf, sorted_src, deg_in, norm_dst, nb + ln0, nb + ln0 + 1,
                        lane, As + ln0 * FEATS, As + (ln0 + 1) * FEATS);
    }
    __syncthreads();
    const int fg = (tid & 31) << 2;
    const int r = tid >> 5;
    float4 acc0 = make_float4(0.f, 0.f, 0.f, 0.f);
    float4 acc1 = make_float4(0.f, 0.f, 0.f, 0.f);
    gemm_2x4(As + r * FEATS, As + (r + 8) * FEATS, W, fg, acc0, acc1);
    float4 bb = *(const float4*)(bias + fg);
    float4 wd = *(const float4*)(Wd + fg);
    float p0 = fmaxf(acc0.x + bb.x, 0.f) * wd.x + fmaxf(acc0.y + bb.y, 0.f) * wd.y +
               fmaxf(acc0.z + bb.z, 0.f) * wd.z + fmaxf(acc0.w + bb.w, 0.f) * wd.w;
    float p1 = fmaxf(acc1.x + bb.x, 0.f) * wd.x + fmaxf(acc1.y + bb.y, 0.f) * wd.y +
               fmaxf(acc1.z + bb.z, 0.f) * wd.z + fmaxf(acc1.w + bb.w, 0.f) * wd.w;
#pragma unroll
    for (int d = 16; d >= 1; d >>= 1) {
        p0 += __shfl_down(p0, d);
        p1 += __shfl_down(p1, d);
    }
    if ((tid & 31) == 0) {
        atomicAdd(&bins[gids[nb + r]], p0);
        atomicAdd(&bins[gids[nb + r + 8]], p1);
    }
    __syncthreads();
    if (tid < N_GRAPHS) {
        float v = bins[tid];
        if (v != 0.f) atomicAdd(&graph_sum[tid], v);
    }
}

__global__ __launch_bounds__(64) void final_kernel(const float* __restrict__ graph_sum,
                                                   const int* __restrict__ graph_cnt,
                                                   const float* __restrict__ bd,
                                                   float* __restrict__ out) {
    int g = threadIdx.x;
    if (g < N_GRAPHS) {
        out[g] = graph_sum[g] / fmaxf((float)graph_cnt[g], 1.f) + bd[0];
    }
}

// ---------------------------------------------------------------------------
extern "C" void kernel_launch(void* const* d_in, const int* in_sizes, int n_in,
                              void* d_out, int out_size, void* d_ws, size_t ws_size,
                              hipStream_t stream) {
    const float* in_feat = (const float*)d_in[0];
    const int*   src     = (const int*)d_in[1];
    const int*   dst     = (const int*)d_in[2];
    const int*   gids    = (const int*)d_in[3];
    const float* W1      = (const float*)d_in[4];
    const float* b1      = (const float*)d_in[5];
    const float* W2      = (const float*)d_in[6];
    const float* b2      = (const float*)d_in[7];
    const float* Wd      = (const float*)d_in[8];
    const float* bd      = (const float*)d_in[9];
    float* out = (float*)d_out;

    char* ws = (char*)d_ws;
    size_t off = 0;
    int* graph_cnt = (int*)(ws + off); off += N_GRAPHS * 4;
    float* graph_sum = (float*)(ws + off); off += N_GRAPHS * 4;
    off = align_up(off, 512);
    unsigned short* counts  = (unsigned short*)(ws + off); off += (size_t)NSLICE * N_NODES * 2;
    off = align_up(off, 512);
    unsigned short* scounts = (unsigned short*)(ws + off); off += (size_t)NSLICE * N_NODES * 2;
    off = align_up(off, 512);
    int* bases = (int*)(ws + off); off += (size_t)NSLICE * N_NODES * 4;
    off = align_up(off, 512);
    int* deg_in  = (int*)(ws + off); off += N_NODES * 4;
    off = align_up(off, 512);
    float* norm_src = (float*)(ws + off); off += N_NODES * 4;
    off = align_up(off, 512);
    float* norm_dst = (float*)(ws + off); off += N_NODES * 4;
    off = align_up(off, 512);
    int* sorted_src = (int*)(ws + off); off += (size_t)N_NODES * CAP * 4 + 4096;
    off = align_up(off, 512);
    __half* xs = (__half*)(ws + off); off += (size_t)N_NODES * FEATS * 2;
    off = align_up(off, 512);
    __half* h  = (__half*)(ws + off); off += (size_t)N_NODES * FEATS * 2;
    (void)ws_size;

    void* args[] = {
        (void*)&in_feat, (void*)&src, (void*)&dst, (void*)&gids,
        (void*)&W1, (void*)&b1, (void*)&W2, (void*)&b2, (void*)&Wd, (void*)&bd,
        (void*)&out,
        (void*)&counts, (void*)&scounts, (void*)&bases, (void*)&deg_in,
        (void*)&norm_src, (void*)&norm_dst, (void*)&sorted_src,
        (void*)&xs, (void*)&h, (void*)&graph_cnt, (void*)&graph_sum
    };
    hipError_t err = hipLaunchCooperativeKernel((const void*)gcn_mono, dim3(NBLK),
                                                dim3(256), args, 0, stream);
    if (err != hipSuccess) {
        (void)hipGetLastError();  // clear sticky error; use known-good path
        hist_kernel<<<2 * NSLICE, 256, 0, stream>>>(src, dst, counts, scounts,
                                                    graph_cnt, graph_sum);
        degnorm_base_kernel<<<(N_NODES + 255) / 256, 256, 0, stream>>>(counts, scounts, gids,
                                                                       bases, deg_in, norm_src,
                                                                       norm_dst, graph_cnt);
        scatter_prescale_kernel<<<NSLICE + PRE_BLOCKS, 256, 0, stream>>>(src, dst, bases,
                                                                         sorted_src, in_feat,
                                                                         norm_src, xs);
        fused_layer1_kernel<<<N_NODES / 16, 256, 0, stream>>>(xs, sorted_src, deg_in, norm_dst,
                                                              W1, b1, norm_src, h);
        fused_layer2_kernel<<<N_NODES / 16, 256, 0, stream>>>(h, sorted_src, deg_in, norm_dst,
                                                              W2, b2, Wd, gids, graph_sum);
        final_kernel<<<1, 64, 0, stream>>>(graph_sum, graph_cnt, bd, out);
    }
}

// Round 5
// 197.992 us; speedup vs baseline: 4.2787x; 4.2787x over previous
//
#include <hip/hip_runtime.h>
#include <hip/hip_fp16.h>

#define N_NODES 10000
#define N_EDGES 640000
#define N_GRAPHS 64
#define FEATS 128
#define CAP 128        // padded per-node edge capacity (mean deg 64; dataset max <=128 proven by R0/R1 layout)
#define CSTRIDE 16     // ints between atomic counters (64B) -> <=2 counters/128B line
#define NTILE (N_NODES / 16)   // 625 GEMM tiles

static inline size_t align_up(size_t x, size_t a) { return (x + a - 1) & ~(a - 1); }

// ---------------------------------------------------------------------------
// D1: zero ctr_in + deg_out + graph_sum (one contiguous region)
__global__ __launch_bounds__(256) void zero_kernel(int4* __restrict__ p, int n4) {
    int i = blockIdx.x * 256 + threadIdx.x;
    if (i < n4) p[i] = make_int4(0, 0, 0, 0);
}

// ---------------------------------------------------------------------------
// D2: blocks 0..624: single-pass scatter — per edge, cursor atomic into padded
//     CSR + out-degree atomic (64B-strided counters: ~128 serialized ops/line).
//     blocks 625..1874: xs = fp16(in_feat) straight convert (no norm dep).
__global__ __launch_bounds__(256) void scatter_convert_kernel(const int* __restrict__ src,
                                                              const int* __restrict__ dst,
                                                              int* __restrict__ ctr_in,
                                                              int* __restrict__ deg_out,
                                                              int* __restrict__ sorted_src,
                                                              const float* __restrict__ in_feat,
                                                              __half* __restrict__ xs) {
    const int tid = threadIdx.x;
    if (blockIdx.x < N_EDGES / 1024) {  // 625 scatter blocks, 4 edges/thread
        const int i = blockIdx.x * 256 + tid;
        int4 sv = ((const int4*)src)[i];
        int4 dv = ((const int4*)dst)[i];
        int slot;
        slot = atomicAdd(&ctr_in[dv.x * CSTRIDE], 1);
        if (slot < CAP) sorted_src[dv.x * CAP + slot] = sv.x;
        atomicAdd(&deg_out[sv.x * CSTRIDE], 1);
        slot = atomicAdd(&ctr_in[dv.y * CSTRIDE], 1);
        if (slot < CAP) sorted_src[dv.y * CAP + slot] = sv.y;
        atomicAdd(&deg_out[sv.y * CSTRIDE], 1);
        slot = atomicAdd(&ctr_in[dv.z * CSTRIDE], 1);
        if (slot < CAP) sorted_src[dv.z * CAP + slot] = sv.z;
        atomicAdd(&deg_out[sv.z * CSTRIDE], 1);
        slot = atomicAdd(&ctr_in[dv.w * CSTRIDE], 1);
        if (slot < CAP) sorted_src[dv.w * CAP + slot] = sv.w;
        atomicAdd(&deg_out[sv.w * CSTRIDE], 1);
    } else {
        const int i = (blockIdx.x - N_EDGES / 1024) * 256 + tid;  // over 320000 float4
        float4 v = ((const float4*)in_feat)[i];
        __half2* o = (__half2*)(xs + (size_t)i * 4);
        o[0] = __floats2half2_rn(v.x, v.y);
        o[1] = __floats2half2_rn(v.z, v.w);
    }
}

// ---------------------------------------------------------------------------
// accumulate one 256B fp16 row into fp32 acc; SC: scale row by sc (norm_src)
template <bool SC>
static __device__ __forceinline__ void acc_row(uint4 v, float sc, float* a) {
    const __half2* hp = (const __half2*)&v;
#pragma unroll
    for (int j = 0; j < 4; j++) {
        float2 f = __half22float2(hp[j]);
        if (SC) {
            a[2 * j]     = fmaf(f.x, sc, a[2 * j]);
            a[2 * j + 1] = fmaf(f.y, sc, a[2 * j + 1]);
        } else {
            a[2 * j]     += f.x;
            a[2 * j + 1] += f.y;
        }
    }
}

// one batch: 4 edges for this quarter-group (16 rows in flight across the wave)
template <bool SC>
static __device__ __forceinline__ void agg_batch(const int* __restrict__ ss,
                                                 const uint4* __restrict__ x4,
                                                 const int* __restrict__ deg_out,
                                                 int base, int c, int l16, float* a) {
    int idx[4];
#pragma unroll
    for (int k = 0; k < 4; k++) idx[k] = ss[base + c + 4 * k];
    uint4 v[4];
#pragma unroll
    for (int k = 0; k < 4; k++) v[k] = x4[idx[k] * 16 + l16];
    float nsv[4] = {1.f, 1.f, 1.f, 1.f};
    if (SC) {
#pragma unroll
        for (int k = 0; k < 4; k++) {
            int d = deg_out[idx[k] * CSTRIDE];
            nsv[k] = rsqrtf((float)(d < 1 ? 1 : d));
        }
    }
#pragma unroll
    for (int k = 0; k < 4; k++) acc_row<SC>(v[k], nsv[k], a);
}

// Aggregate TWO dst nodes per wave concurrently; deg/norm from padded counters.
template <bool SC>
static __device__ __forceinline__ void wave_aggregate2(const __half* __restrict__ X,
                                                       const int* __restrict__ ss,
                                                       const int* __restrict__ ctr_in,
                                                       const int* __restrict__ deg_out,
                                                       int n0, int n1, int lane,
                                                       float* __restrict__ r0,
                                                       float* __restrict__ r1) {
    const int grp = lane >> 4, l16 = lane & 15;
    const int s0 = n0 * CAP, s1 = n1 * CAP;
    const int d0 = ctr_in[n0 * CSTRIDE], d1 = ctr_in[n1 * CSTRIDE];
    const float nd0 = rsqrtf((float)(d0 < 1 ? 1 : d0));
    const float nd1 = rsqrtf((float)(d1 < 1 ? 1 : d1));
    const int c0n = d0 < CAP ? d0 : CAP;
    const int c1n = d1 < CAP ? d1 : CAP;
    const uint4* __restrict__ x4 = (const uint4*)X;  // row = 16 uint4 (256 B)
    float a0[8] = {0.f, 0.f, 0.f, 0.f, 0.f, 0.f, 0.f, 0.f};
    float a1[8] = {0.f, 0.f, 0.f, 0.f, 0.f, 0.f, 0.f, 0.f};
    int c0 = grp, c1 = grp;
    while (c0 + 12 < c0n && c1 + 12 < c1n) {
        agg_batch<SC>(ss, x4, deg_out, s0, c0, l16, a0);
        agg_batch<SC>(ss, x4, deg_out, s1, c1, l16, a1);
        c0 += 16; c1 += 16;
    }
    for (; c0 + 12 < c0n; c0 += 16) agg_batch<SC>(ss, x4, deg_out, s0, c0, l16, a0);
    for (; c1 + 12 < c1n; c1 += 16) agg_batch<SC>(ss, x4, deg_out, s1, c1, l16, a1);
    for (; c0 < c0n; c0 += 4) {
        int idx = ss[s0 + c0];
        float nsv = 1.f;
        if (SC) { int d = deg_out[idx * CSTRIDE]; nsv = rsqrtf((float)(d < 1 ? 1 : d)); }
        acc_row<SC>(x4[idx * 16 + l16], nsv, a0);
    }
    for (; c1 < c1n; c1 += 4) {
        int idx = ss[s1 + c1];
        float nsv = 1.f;
        if (SC) { int d = deg_out[idx * CSTRIDE]; nsv = rsqrtf((float)(d < 1 ? 1 : d)); }
        acc_row<SC>(x4[idx * 16 + l16], nsv, a1);
    }
#pragma unroll
    for (int j = 0; j < 8; j++) {
        a0[j] += __shfl_xor(a0[j], 16);
        a0[j] += __shfl_xor(a0[j], 32);
        a1[j] += __shfl_xor(a1[j], 16);
        a1[j] += __shfl_xor(a1[j], 32);
    }
    if (grp == 0) {
        *(float4*)(r0 + l16 * 8)     = make_float4(a0[0] * nd0, a0[1] * nd0, a0[2] * nd0, a0[3] * nd0);
        *(float4*)(r0 + l16 * 8 + 4) = make_float4(a0[4] * nd0, a0[5] * nd0, a0[6] * nd0, a0[7] * nd0);
        *(float4*)(r1 + l16 * 8)     = make_float4(a1[0] * nd1, a1[1] * nd1, a1[2] * nd1, a1[3] * nd1);
        *(float4*)(r1 + l16 * 8 + 4) = make_float4(a1[4] * nd1, a1[5] * nd1, a1[6] * nd1, a1[7] * nd1);
    }
}

// GEMM inner: 2 rows (r, r+8) x 4 cols from LDS As against W, fp32 acc
static __device__ __forceinline__ void gemm_2x4(const float* __restrict__ a0p,
                                                const float* __restrict__ a1p,
                                                const float* __restrict__ W, int fg,
                                                float4& acc0, float4& acc1) {
#pragma unroll 4
    for (int k = 0; k < FEATS; k++) {
        float a0 = a0p[k];
        float a1 = a1p[k];
        float4 w = *(const float4*)(W + k * FEATS + fg);
        acc0.x = fmaf(a0, w.x, acc0.x); acc0.y = fmaf(a0, w.y, acc0.y);
        acc0.z = fmaf(a0, w.z, acc0.z); acc0.w = fmaf(a0, w.w, acc0.w);
        acc1.x = fmaf(a1, w.x, acc1.x); acc1.y = fmaf(a1, w.y, acc1.y);
        acc1.z = fmaf(a1, w.z, acc1.z); acc1.w = fmaf(a1, w.w, acc1.w);
    }
}

// ---------------------------------------------------------------------------
// D3: layer1 — aggregate (per-edge norm_src) into LDS fp32, GEMM W1, relu,
//     write h pre-scaled by norm_src[node] (fp16) for layer2.
__global__ __launch_bounds__(256) void fused_layer1_kernel(const __half* __restrict__ xs,
                                                           const int* __restrict__ sorted_src,
                                                           const int* __restrict__ ctr_in,
                                                           const int* __restrict__ deg_out,
                                                           const float* __restrict__ W,
                                                           const float* __restrict__ bias,
                                                           __half* __restrict__ out) {
    __shared__ float As[16 * FEATS];
    const int tid = threadIdx.x;
    const int nb = blockIdx.x * 16;
    const int wave = tid >> 6, lane = tid & 63;
#pragma unroll
    for (int p = 0; p < 2; p++) {
        int ln0 = wave * 4 + 2 * p;
        wave_aggregate2<true>(xs, sorted_src, ctr_in, deg_out, nb + ln0, nb + ln0 + 1,
                              lane, As + ln0 * FEATS, As + (ln0 + 1) * FEATS);
    }
    __syncthreads();
    const int fg = (tid & 31) << 2;
    const int r = tid >> 5;
    float4 acc0 = make_float4(0.f, 0.f, 0.f, 0.f);
    float4 acc1 = make_float4(0.f, 0.f, 0.f, 0.f);
    gemm_2x4(As + r * FEATS, As + (r + 8) * FEATS, W, fg, acc0, acc1);
    float4 bb = *(const float4*)(bias + fg);
    const int gn0 = nb + r, gn1 = nb + r + 8;
    const int do0 = deg_out[gn0 * CSTRIDE], do1 = deg_out[gn1 * CSTRIDE];
    const float s0 = rsqrtf((float)(do0 < 1 ? 1 : do0));
    const float s1 = rsqrtf((float)(do1 < 1 ? 1 : do1));
    __half2 h00 = __floats2half2_rn(fmaxf(acc0.x + bb.x, 0.f) * s0,
                                    fmaxf(acc0.y + bb.y, 0.f) * s0);
    __half2 h01 = __floats2half2_rn(fmaxf(acc0.z + bb.z, 0.f) * s0,
                                    fmaxf(acc0.w + bb.w, 0.f) * s0);
    __half2 h10 = __floats2half2_rn(fmaxf(acc1.x + bb.x, 0.f) * s1,
                                    fmaxf(acc1.y + bb.y, 0.f) * s1);
    __half2 h11 = __floats2half2_rn(fmaxf(acc1.z + bb.z, 0.f) * s1,
                                    fmaxf(acc1.w + bb.w, 0.f) * s1);
    __half2* o0 = (__half2*)(out + (size_t)gn0 * FEATS + fg);
    __half2* o1 = (__half2*)(out + (size_t)gn1 * FEATS + fg);
    o0[0] = h00; o0[1] = h01;
    o1[0] = h10; o1[1] = h11;
}

// ---------------------------------------------------------------------------
// D4: layer2+pool — aggregate pre-scaled h (plain adds), GEMM W2, relu,
//     dot Wd, LDS 64-bin accumulate, few global atomics per block.
__global__ __launch_bounds__(256) void fused_layer2_kernel(const __half* __restrict__ hbuf,
                                                           const int* __restrict__ sorted_src,
                                                           const int* __restrict__ ctr_in,
                                                           const float* __restrict__ W,
                                                           const float* __restrict__ bias,
                                                           const float* __restrict__ Wd,
                                                           const int* __restrict__ gids,
                                                           float* __restrict__ graph_sum) {
    __shared__ float As[16 * FEATS];
    __shared__ float bins[N_GRAPHS];
    const int tid = threadIdx.x;
    const int nb = blockIdx.x * 16;
    const int wave = tid >> 6, lane = tid & 63;
    if (tid < N_GRAPHS) bins[tid] = 0.f;
#pragma unroll
    for (int p = 0; p < 2; p++) {
        int ln0 = wave * 4 + 2 * p;
        wave_aggregate2<false>(hbuf, sorted_src, ctr_in, (const int*)0, nb + ln0, nb + ln0 + 1,
                               lane, As + ln0 * FEATS, As + (ln0 + 1) * FEATS);
    }
    __syncthreads();
    const int fg = (tid & 31) << 2;
    const int r = tid >> 5;
    float4 acc0 = make_float4(0.f, 0.f, 0.f, 0.f);
    float4 acc1 = make_float4(0.f, 0.f, 0.f, 0.f);
    gemm_2x4(As + r * FEATS, As + (r + 8) * FEATS, W, fg, acc0, acc1);
    float4 bb = *(const float4*)(bias + fg);
    float4 wd = *(const float4*)(Wd + fg);
    float p0 = fmaxf(acc0.x + bb.x, 0.f) * wd.x + fmaxf(acc0.y + bb.y, 0.f) * wd.y +
               fmaxf(acc0.z + bb.z, 0.f) * wd.z + fmaxf(acc0.w + bb.w, 0.f) * wd.w;
    float p1 = fmaxf(acc1.x + bb.x, 0.f) * wd.x + fmaxf(acc1.y + bb.y, 0.f) * wd.y +
               fmaxf(acc1.z + bb.z, 0.f) * wd.z + fmaxf(acc1.w + bb.w, 0.f) * wd.w;
#pragma unroll
    for (int d = 16; d >= 1; d >>= 1) {
        p0 += __shfl_down(p0, d);
        p1 += __shfl_down(p1, d);
    }
    if ((tid & 31) == 0) {
        atomicAdd(&bins[gids[nb + r]], p0);
        atomicAdd(&bins[gids[nb + r + 8]], p1);
    }
    __syncthreads();
    if (tid < N_GRAPHS) {
        float v = bins[tid];
        if (v != 0.f) atomicAdd(&graph_sum[tid], v);
    }
}

// ---------------------------------------------------------------------------
// D5: final — per-graph node counts via binary search on sorted gids.
static __device__ __forceinline__ int lower_bound_dev(const int* __restrict__ g, int key) {
    int lo = 0, hi = N_NODES;
    while (lo < hi) {
        int mid = (lo + hi) >> 1;
        if (g[mid] < key) lo = mid + 1; else hi = mid;
    }
    return lo;
}

__global__ __launch_bounds__(64) void final_kernel(const float* __restrict__ graph_sum,
                                                   const int* __restrict__ gids,
                                                   const float* __restrict__ bd,
                                                   float* __restrict__ out) {
    int g = threadIdx.x;
    if (g < N_GRAPHS) {
        int cnt = lower_bound_dev(gids, g + 1) - lower_bound_dev(gids, g);
        out[g] = graph_sum[g] / fmaxf((float)cnt, 1.f) + bd[0];
    }
}

// ---------------------------------------------------------------------------
extern "C" void kernel_launch(void* const* d_in, const int* in_sizes, int n_in,
                              void* d_out, int out_size, void* d_ws, size_t ws_size,
                              hipStream_t stream) {
    const float* in_feat = (const float*)d_in[0];
    const int*   src     = (const int*)d_in[1];
    const int*   dst     = (const int*)d_in[2];
    const int*   gids    = (const int*)d_in[3];
    const float* W1      = (const float*)d_in[4];
    const float* b1      = (const float*)d_in[5];
    const float* W2      = (const float*)d_in[6];
    const float* b2      = (const float*)d_in[7];
    const float* Wd      = (const float*)d_in[8];
    const float* bd      = (const float*)d_in[9];
    float* out = (float*)d_out;

    char* ws = (char*)d_ws;
    size_t off = 0;
    // contiguous zero region: ctr_in | deg_out | graph_sum
    int* ctr_in = (int*)(ws + off);  off += (size_t)N_NODES * CSTRIDE * 4;   // 640 KB
    int* deg_out = (int*)(ws + off); off += (size_t)N_NODES * CSTRIDE * 4;   // 640 KB
    float* graph_sum = (float*)(ws + off); off += N_GRAPHS * 4;
    size_t zero_bytes = align_up(off, 16);
    off = align_up(off, 512);
    int* sorted_src = (int*)(ws + off); off += (size_t)N_NODES * CAP * 4;    // 5.12 MB
    off = align_up(off, 512);
    __half* xs = (__half*)(ws + off); off += (size_t)N_NODES * FEATS * 2;    // 2.56 MB
    off = align_up(off, 512);
    __half* h  = (__half*)(ws + off); off += (size_t)N_NODES * FEATS * 2;    // 2.56 MB
    (void)ws_size;  // ~11.6 MB used

    const int zero_n4 = (int)(zero_bytes / 16);
    zero_kernel<<<(zero_n4 + 255) / 256, 256, 0, stream>>>((int4*)ws, zero_n4);

    scatter_convert_kernel<<<N_EDGES / 1024 + N_NODES * (FEATS / 4) / 256, 256, 0, stream>>>(
        src, dst, ctr_in, deg_out, sorted_src, in_feat, xs);

    fused_layer1_kernel<<<NTILE, 256, 0, stream>>>(xs, sorted_src, ctr_in, deg_out,
                                                   W1, b1, h);
    fused_layer2_kernel<<<NTILE, 256, 0, stream>>>(h, sorted_src, ctr_in,
                                                   W2, b2, Wd, gids, graph_sum);
    final_kernel<<<1, 64, 0, stream>>>(graph_sum, gids, bd, out);
}

// Round 6
// 181.349 us; speedup vs baseline: 4.6714x; 1.0918x over previous
//
#include <hip/hip_runtime.h>
#include <hip/hip_fp16.h>

#define N_NODES 10000
#define N_EDGES 640000
#define N_GRAPHS 64
#define FEATS 128

#define NSLICE 128
#define EPS (N_EDGES / NSLICE)   // 5000 edges per slice
#define CAP 128                  // padded per-node edge capacity
#define PRE_BLOCKS 1250          // 320000 float4 / 256
#define NTILE (N_NODES / 16)     // 625 layer tiles of 16 nodes

static inline size_t align_up(size_t x, size_t a) { return (x + a - 1) & ~(a - 1); }

// ---------------------------------------------------------------------------
// 1) HIST (R1 verbatim): blocks 0..127 dst-slices, 128..255 src-slices.
__global__ __launch_bounds__(256) void hist_kernel(const int* __restrict__ src,
                                                   const int* __restrict__ dst,
                                                   unsigned short* __restrict__ counts,
                                                   unsigned short* __restrict__ scounts,
                                                   int* __restrict__ graph_cnt,
                                                   float* __restrict__ graph_sum) {
    __shared__ int h[N_NODES];
    const int tid = threadIdx.x;
    const int b = blockIdx.x;
    if (b == 0 && tid < 2 * N_GRAPHS) {
        if (tid < N_GRAPHS) graph_cnt[tid] = 0;
        else                graph_sum[tid - N_GRAPHS] = 0.f;
    }
    const bool is_dst = (b < NSLICE);
    const int slice = is_dst ? b : b - NSLICE;
    const int* col = is_dst ? dst : src;
    unsigned short* outp = (is_dst ? counts : scounts) + slice * N_NODES;

    for (int i = tid; i < N_NODES; i += 256) h[i] = 0;
    __syncthreads();
    const int4* c4 = (const int4*)(col + slice * EPS);
    for (int i = tid; i < EPS / 4; i += 256) {
        int4 v = c4[i];
        atomicAdd(&h[v.x], 1);
        atomicAdd(&h[v.y], 1);
        atomicAdd(&h[v.z], 1);
        atomicAdd(&h[v.w], 1);
    }
    __syncthreads();
    for (int i = tid; i < N_NODES; i += 256) outp[i] = (unsigned short)h[i];
}

// ---------------------------------------------------------------------------
// 2) DEGNORM+BASE (R1 verbatim): scan counts -> bases; degrees/norms/graph cnt.
__global__ __launch_bounds__(64) void degnorm_base_kernel(const unsigned short* __restrict__ counts,
                                                          const unsigned short* __restrict__ scounts,
                                                          const int* __restrict__ gids,
                                                          int* __restrict__ bases,
                                                          int* __restrict__ deg_in,
                                                          float* __restrict__ norm_src,
                                                          float* __restrict__ norm_dst,
                                                          int* __restrict__ graph_cnt) {
    __shared__ int gcnt[N_GRAPHS];
    const int tid = threadIdx.x;
    gcnt[tid] = 0;  // 64 threads == N_GRAPHS
    __syncthreads();
    int n = blockIdx.x * 64 + tid;
    if (n < N_NODES) {
        int run = n * CAP;
        for (int s = 0; s < NSLICE; s++) {
            int c = counts[s * N_NODES + n];
            bases[s * N_NODES + n] = run;
            run += c;
        }
        int di = run - n * CAP;
        int dou = 0;
        for (int s = 0; s < NSLICE; s++) dou += scounts[s * N_NODES + n];
        deg_in[n] = di;
        norm_dst[n] = rsqrtf((float)(di < 1 ? 1 : di));
        norm_src[n] = rsqrtf((float)(dou < 1 ? 1 : dou));
        atomicAdd(&gcnt[gids[n]], 1);
    }
    __syncthreads();
    if (gcnt[tid]) atomicAdd(&graph_cnt[tid], gcnt[tid]);
}

// ---------------------------------------------------------------------------
// 3) SCATTER+PRESCALE (R1 verbatim): blocks 0..127 LDS-cursor scatter;
//    blocks 128..1377 xs = fp16(in_feat * norm_src).
__global__ __launch_bounds__(256) void scatter_prescale_kernel(const int* __restrict__ src,
                                                               const int* __restrict__ dst,
                                                               const int* __restrict__ bases,
                                                               int* __restrict__ sorted_src,
                                                               const float* __restrict__ in_feat,
                                                               const float* __restrict__ norm_src,
                                                               __half* __restrict__ xs) {
    const int tid = threadIdx.x;
    if (blockIdx.x < NSLICE) {
        __shared__ int cur[N_NODES];
        const int s = blockIdx.x;
        for (int i = tid; i < N_NODES; i += 256) cur[i] = bases[s * N_NODES + i];
        __syncthreads();
        const int4* s4 = (const int4*)(src + s * EPS);
        const int4* d4 = (const int4*)(dst + s * EPS);
        for (int i = tid; i < EPS / 4; i += 256) {
            int4 sv = s4[i];
            int4 dv = d4[i];
            int p;
            p = atomicAdd(&cur[dv.x], 1); sorted_src[p] = sv.x;
            p = atomicAdd(&cur[dv.y], 1); sorted_src[p] = sv.y;
            p = atomicAdd(&cur[dv.z], 1); sorted_src[p] = sv.z;
            p = atomicAdd(&cur[dv.w], 1); sorted_src[p] = sv.w;
        }
    } else {
        int i = (blockIdx.x - NSLICE) * 256 + tid;  // over 320000 float4
        if (i < N_NODES * (FEATS / 4)) {
            int n = i >> 5;
            float4 v = ((const float4*)in_feat)[i];
            float s = norm_src[n];
            __half2 h0 = __floats2half2_rn(v.x * s, v.y * s);
            __half2 h1 = __floats2half2_rn(v.z * s, v.w * s);
            __half2* o = (__half2*)(xs + (size_t)i * 4);
            o[0] = h0; o[1] = h1;
        }
    }
}

// ---------------------------------------------------------------------------
// accumulate one 256B fp16 row (uint4 per 16-lane group) into fp32 acc
static __device__ __forceinline__ void acc_row(uint4 v, float* a) {
    const __half2* hp = (const __half2*)&v;
#pragma unroll
    for (int j = 0; j < 4; j++) {
        float2 f = __half22float2(hp[j]);
        a[2 * j]     += f.x;
        a[2 * j + 1] += f.y;
    }
}

// one batch: 4 edges for this quarter-group (16 rows in flight across the wave)
static __device__ __forceinline__ void agg_batch(const int* __restrict__ ss,
                                                 const uint4* __restrict__ x4,
                                                 int base, int c, int l16, float* a) {
    int idx[4];
#pragma unroll
    for (int k = 0; k < 4; k++) idx[k] = ss[base + c + 4 * k];
    uint4 v[4];
#pragma unroll
    for (int k = 0; k < 4; k++) v[k] = x4[idx[k] * 16 + l16];
#pragma unroll
    for (int k = 0; k < 4; k++) acc_row(v[k], a);
}

// Aggregate TWO dst nodes per wave concurrently (R1 verbatim).
static __device__ __forceinline__ void wave_aggregate2(const __half* __restrict__ X,
                                                       const int* __restrict__ ss,
                                                       const int* __restrict__ deg_in,
                                                       const float* __restrict__ nrm,
                                                       int n0, int n1, int lane,
                                                       float* __restrict__ r0,
                                                       float* __restrict__ r1) {
    const int grp = lane >> 4, l16 = lane & 15;
    const int s0 = n0 * CAP, s1 = n1 * CAP;
    const int c0n = deg_in[n0], c1n = deg_in[n1];
    const uint4* __restrict__ x4 = (const uint4*)X;  // row = 16 uint4 (256 B)
    float a0[8] = {0.f, 0.f, 0.f, 0.f, 0.f, 0.f, 0.f, 0.f};
    float a1[8] = {0.f, 0.f, 0.f, 0.f, 0.f, 0.f, 0.f, 0.f};
    int c0 = grp, c1 = grp;
    while (c0 + 12 < c0n && c1 + 12 < c1n) {
        agg_batch(ss, x4, s0, c0, l16, a0);
        agg_batch(ss, x4, s1, c1, l16, a1);
        c0 += 16; c1 += 16;
    }
    for (; c0 + 12 < c0n; c0 += 16) agg_batch(ss, x4, s0, c0, l16, a0);
    for (; c1 + 12 < c1n; c1 += 16) agg_batch(ss, x4, s1, c1, l16, a1);
    for (; c0 < c0n; c0 += 4) acc_row(x4[ss[s0 + c0] * 16 + l16], a0);
    for (; c1 < c1n; c1 += 4) acc_row(x4[ss[s1 + c1] * 16 + l16], a1);
#pragma unroll
    for (int j = 0; j < 8; j++) {
        a0[j] += __shfl_xor(a0[j], 16);
        a0[j] += __shfl_xor(a0[j], 32);
        a1[j] += __shfl_xor(a1[j], 16);
        a1[j] += __shfl_xor(a1[j], 32);
    }
    if (grp == 0) {
        const float nd0 = nrm[n0], nd1 = nrm[n1];
        *(float4*)(r0 + l16 * 8)     = make_float4(a0[0] * nd0, a0[1] * nd0, a0[2] * nd0, a0[3] * nd0);
        *(float4*)(r0 + l16 * 8 + 4) = make_float4(a0[4] * nd0, a0[5] * nd0, a0[6] * nd0, a0[7] * nd0);
        *(float4*)(r1 + l16 * 8)     = make_float4(a1[0] * nd1, a1[1] * nd1, a1[2] * nd1, a1[3] * nd1);
        *(float4*)(r1 + l16 * 8 + 4) = make_float4(a1[4] * nd1, a1[5] * nd1, a1[6] * nd1, a1[7] * nd1);
    }
}

// GEMM inner: ONE row x 4 cols from LDS As against W, fp32 acc
static __device__ __forceinline__ void gemm_1x4(const float* __restrict__ ap,
                                                const float* __restrict__ W, int fg,
                                                float4& acc) {
#pragma unroll 4
    for (int k = 0; k < FEATS; k++) {
        float a = ap[k];
        float4 w = *(const float4*)(W + k * FEATS + fg);
        acc.x = fmaf(a, w.x, acc.x); acc.y = fmaf(a, w.y, acc.y);
        acc.z = fmaf(a, w.z, acc.z); acc.w = fmaf(a, w.w, acc.w);
    }
}

// ---------------------------------------------------------------------------
// 4) FUSED LAYER 1 — 512 threads (8 waves): each wave aggregates ONE node
//    pair (2x TLP, half the per-wave serial chain vs R1); GEMM 1 row/thread.
__global__ __launch_bounds__(512) void fused_layer1_kernel(const __half* __restrict__ xs,
                                                           const int* __restrict__ sorted_src,
                                                           const int* __restrict__ deg_in,
                                                           const float* __restrict__ norm_dst,
                                                           const float* __restrict__ W,
                                                           const float* __restrict__ bias,
                                                           const float* __restrict__ scale,
                                                           __half* __restrict__ out) {
    __shared__ float As[16 * FEATS];
    const int tid = threadIdx.x;
    const int nb = blockIdx.x * 16;
    const int wave = tid >> 6, lane = tid & 63;
    const int ln0 = wave * 2;
    wave_aggregate2(xs, sorted_src, deg_in, norm_dst, nb + ln0, nb + ln0 + 1,
                    lane, As + ln0 * FEATS, As + (ln0 + 1) * FEATS);
    __syncthreads();
    const int fg = (tid & 31) << 2;
    const int r = tid >> 5;  // 0..15
    float4 acc = make_float4(0.f, 0.f, 0.f, 0.f);
    gemm_1x4(As + r * FEATS, W, fg, acc);
    float4 bb = *(const float4*)(bias + fg);
    const int gn = nb + r;
    const float s = scale[gn];
    __half2 h0 = __floats2half2_rn(fmaxf(acc.x + bb.x, 0.f) * s,
                                   fmaxf(acc.y + bb.y, 0.f) * s);
    __half2 h1 = __floats2half2_rn(fmaxf(acc.z + bb.z, 0.f) * s,
                                   fmaxf(acc.w + bb.w, 0.f) * s);
    __half2* o = (__half2*)(out + (size_t)gn * FEATS + fg);
    o[0] = h0; o[1] = h1;
}

// ---------------------------------------------------------------------------
// 5) FUSED LAYER 2 + POOL — 512 threads, same restructure.
__global__ __launch_bounds__(512) void fused_layer2_kernel(const __half* __restrict__ hbuf,
                                                           const int* __restrict__ sorted_src,
                                                           const int* __restrict__ deg_in,
                                                           const float* __restrict__ norm_dst,
                                                           const float* __restrict__ W,
                                                           const float* __restrict__ bias,
                                                           const float* __restrict__ Wd,
                                                           const int* __restrict__ gids,
                                                           float* __restrict__ graph_sum) {
    __shared__ float As[16 * FEATS];
    __shared__ float bins[N_GRAPHS];
    const int tid = threadIdx.x;
    const int nb = blockIdx.x * 16;
    const int wave = tid >> 6, lane = tid & 63;
    if (tid < N_GRAPHS) bins[tid] = 0.f;
    const int ln0 = wave * 2;
    wave_aggregate2(hbuf, sorted_src, deg_in, norm_dst, nb + ln0, nb + ln0 + 1,
                    lane, As + ln0 * FEATS, As + (ln0 + 1) * FEATS);
    __syncthreads();
    const int fg = (tid & 31) << 2;
    const int r = tid >> 5;  // 0..15
    float4 acc = make_float4(0.f, 0.f, 0.f, 0.f);
    gemm_1x4(As + r * FEATS, W, fg, acc);
    float4 bb = *(const float4*)(bias + fg);
    float4 wd = *(const float4*)(Wd + fg);
    float p0 = fmaxf(acc.x + bb.x, 0.f) * wd.x + fmaxf(acc.y + bb.y, 0.f) * wd.y +
               fmaxf(acc.z + bb.z, 0.f) * wd.z + fmaxf(acc.w + bb.w, 0.f) * wd.w;
    // lane0 of each 32-lane r-group ends with the exact sum of its 32 lanes
#pragma unroll
    for (int d = 16; d >= 1; d >>= 1) p0 += __shfl_down(p0, d);
    if ((tid & 31) == 0) atomicAdd(&bins[gids[nb + r]], p0);
    __syncthreads();
    if (tid < N_GRAPHS) {
        float v = bins[tid];
        if (v != 0.f) atomicAdd(&graph_sum[tid], v);
    }
}

// ---------------------------------------------------------------------------
// 6) final: out[g] = graph_sum[g] / max(cnt,1) + bd
__global__ __launch_bounds__(64) void final_kernel(const float* __restrict__ graph_sum,
                                                   const int* __restrict__ graph_cnt,
                                                   const float* __restrict__ bd,
                                                   float* __restrict__ out) {
    int g = threadIdx.x;
    if (g < N_GRAPHS) {
        out[g] = graph_sum[g] / fmaxf((float)graph_cnt[g], 1.f) + bd[0];
    }
}

// ---------------------------------------------------------------------------
extern "C" void kernel_launch(void* const* d_in, const int* in_sizes, int n_in,
                              void* d_out, int out_size, void* d_ws, size_t ws_size,
                              hipStream_t stream) {
    const float* in_feat = (const float*)d_in[0];
    const int*   src     = (const int*)d_in[1];
    const int*   dst     = (const int*)d_in[2];
    const int*   gids    = (const int*)d_in[3];
    const float* W1      = (const float*)d_in[4];
    const float* b1      = (const float*)d_in[5];
    const float* W2      = (const float*)d_in[6];
    const float* b2      = (const float*)d_in[7];
    const float* Wd      = (const float*)d_in[8];
    const float* bd      = (const float*)d_in[9];
    float* out = (float*)d_out;

    char* ws = (char*)d_ws;
    size_t off = 0;
    int* graph_cnt = (int*)(ws + off); off += N_GRAPHS * 4;
    float* graph_sum = (float*)(ws + off); off += N_GRAPHS * 4;
    off = align_up(off, 512);
    unsigned short* counts  = (unsigned short*)(ws + off); off += (size_t)NSLICE * N_NODES * 2;
    off = align_up(off, 512);
    unsigned short* scounts = (unsigned short*)(ws + off); off += (size_t)NSLICE * N_NODES * 2;
    off = align_up(off, 512);
    int* bases = (int*)(ws + off); off += (size_t)NSLICE * N_NODES * 4;
    off = align_up(off, 512);
    int* deg_in  = (int*)(ws + off); off += N_NODES * 4;
    off = align_up(off, 512);
    float* norm_src = (float*)(ws + off); off += N_NODES * 4;
    off = align_up(off, 512);
    float* norm_dst = (float*)(ws + off); off += N_NODES * 4;
    off = align_up(off, 512);
    int* sorted_src = (int*)(ws + off); off += (size_t)N_NODES * CAP * 4 + 4096;
    off = align_up(off, 512);
    __half* xs = (__half*)(ws + off); off += (size_t)N_NODES * FEATS * 2;
    off = align_up(off, 512);
    __half* h  = (__half*)(ws + off); off += (size_t)N_NODES * FEATS * 2;
    (void)ws_size;  // ~20.6 MB used

    hist_kernel<<<2 * NSLICE, 256, 0, stream>>>(src, dst, counts, scounts,
                                                graph_cnt, graph_sum);
    degnorm_base_kernel<<<(N_NODES + 63) / 64, 64, 0, stream>>>(counts, scounts, gids,
                                                                bases, deg_in, norm_src,
                                                                norm_dst, graph_cnt);
    scatter_prescale_kernel<<<NSLICE + PRE_BLOCKS, 256, 0, stream>>>(src, dst, bases,
                                                                     sorted_src, in_feat,
                                                                     norm_src, xs);

    fused_layer1_kernel<<<NTILE, 512, 0, stream>>>(xs, sorted_src, deg_in, norm_dst,
                                                   W1, b1, norm_src, h);
    fused_layer2_kernel<<<NTILE, 512, 0, stream>>>(h, sorted_src, deg_in, norm_dst,
                                                   W2, b2, Wd, gids, graph_sum);

    final_kernel<<<1, 64, 0, stream>>>(graph_sum, graph_cnt, bd, out);
}